// Round 1
// baseline (286.462 us; speedup 1.0000x reference)
//
#include <hip/hip_runtime.h>
#include <math.h>

#define F1 64   // input/hidden features
#define F2 40   // classes
#define NB 1024     // buckets for CSR build (bsh=7 -> 128 nodes/bucket)
#define TILE 4096   // edges per k_bscatter/k_bhist block
#define FCAP 3200   // max staged edges/bucket in k_final (25.6 KB); mean 2046, sigma 45

typedef unsigned int uint;

// ---------- bf16 helpers ----------
__device__ inline unsigned short f2bf(float f) {
    unsigned u = __float_as_uint(f);
    unsigned r = (u + 0x7FFFu + ((u >> 16) & 1u)) >> 16;   // RNE
    return (unsigned short)r;
}
__device__ inline uint packbf(float lo, float hi) {
    return (uint)f2bf(lo) | ((uint)f2bf(hi) << 16);
}
__device__ inline float bf_lo(uint u) { return __uint_as_float(u << 16); }
__device__ inline float bf_hi(uint u) { return __uint_as_float(u & 0xFFFF0000u); }

// ---------- pass 1a: bucket histogram ----------
__global__ __launch_bounds__(256) void k_bhist(const int* __restrict__ dst,
                                               int* __restrict__ bcnt, int e, int bsh) {
    __shared__ int h[NB];
    int tid = threadIdx.x;
    for (int i = tid; i < NB; i += 256) h[i] = 0;
    __syncthreads();
    int base = blockIdx.x * TILE;
    int lim = min(base + TILE, e);
    for (int i = base + tid; i < lim; i += 256) atomicAdd(&h[dst[i] >> bsh], 1);
    __syncthreads();
    for (int i = tid; i < NB; i += 256) if (h[i]) atomicAdd(&bcnt[i], h[i]);
}

// ---------- pass 1b: scan of bucket counts ----------
__global__ __launch_bounds__(NB) void k_bscan(const int* __restrict__ bcnt,
                                              int* __restrict__ bptr, int* __restrict__ gcur,
                                              int* __restrict__ row_ptr, int n, int e) {
    __shared__ int sh[NB];
    int t = threadIdx.x;
    sh[t] = bcnt[t];
    __syncthreads();
    for (int off = 1; off < NB; off <<= 1) {
        int v = (t >= off) ? sh[t - off] : 0;
        __syncthreads();
        sh[t] += v;
        __syncthreads();
    }
    int ex = t ? sh[t - 1] : 0;
    bptr[t] = ex;
    gcur[t] = ex;
    if (t == NB - 1) bptr[NB] = sh[NB - 1];
    if (t == 0) row_ptr[n] = e;
}

// ---------- pass 1c: bucket (src,dst) pairs ----------
__global__ __launch_bounds__(256) void k_bscatter(const int* __restrict__ src,
                                                  const int* __restrict__ dst,
                                                  int* gcur,
                                                  unsigned long long* __restrict__ pairs,
                                                  int e, int bsh) {
    __shared__ int lhist[NB];
    __shared__ int lstart[NB];
    __shared__ int delta[NB];
    __shared__ unsigned long long stage[TILE];
    int tid = threadIdx.x;
    for (int i = tid; i < NB; i += 256) lhist[i] = 0;
    __syncthreads();
    int base = blockIdx.x * TILE;
    int cnt = min(TILE, e - base);
    int sA[16], dA[16], rA[16];
#pragma unroll
    for (int k = 0; k < 16; ++k) {
        int i = base + k * 256 + tid;
        if (i < e) {
            sA[k] = src[i];
            dA[k] = dst[i];
            rA[k] = atomicAdd(&lhist[dA[k] >> bsh], 1);
        }
    }
    __syncthreads();
    if (tid < 64) {
        const int per = NB / 64;
        int v[per];
        int b0 = tid * per, s = 0;
#pragma unroll
        for (int j = 0; j < per; ++j) { v[j] = lhist[b0 + j]; s += v[j]; }
        int sc = s;
        for (int o = 1; o < 64; o <<= 1) { int u = __shfl_up(sc, o); if (tid >= o) sc += u; }
        int ex = sc - s;
#pragma unroll
        for (int j = 0; j < per; ++j) { lstart[b0 + j] = ex; ex += v[j]; }
    }
    __syncthreads();
    for (int i = tid; i < NB; i += 256) {
        int c = lhist[i];
        if (c) delta[i] = atomicAdd(&gcur[i], c) - lstart[i];
    }
    __syncthreads();
#pragma unroll
    for (int k = 0; k < 16; ++k) {
        int i = base + k * 256 + tid;
        if (i < e) {
            int b = dA[k] >> bsh;
            stage[lstart[b] + rA[k]] =
                ((unsigned long long)(unsigned)sA[k] << 32) | (unsigned)dA[k];
        }
    }
    __syncthreads();
    for (int p = tid; p < cnt; p += 256) {
        unsigned long long pr = stage[p];
        int b = ((int)(unsigned)pr) >> bsh;
        pairs[delta[b] + p] = pr;
    }
}

// ---------- pass 2: per-bucket finalize: row_ptr, dinv, srcs ----------
__global__ __launch_bounds__(256) void k_final(const unsigned long long* __restrict__ pairs,
                                               const int* __restrict__ bptr,
                                               int* __restrict__ srcs,
                                               int* __restrict__ row_ptr,
                                               float* __restrict__ dinv,
                                               int n, int bsh) {
    __shared__ int ldeg[128];
    __shared__ int lrow[128];
    __shared__ int lcur[128];
    __shared__ unsigned long long stg[FCAP];
    int b = blockIdx.x, tid = threadIdx.x;
    int beg = bptr[b], cnt = bptr[b + 1] - beg;
    int node0 = b << bsh;
    int bnodes = 1 << bsh;   // 128
    for (int i = tid; i < bnodes; i += 256) { ldeg[i] = 0; lcur[i] = 0; }
    bool fit = cnt <= FCAP;
    __syncthreads();
    if (fit) {
        for (int p = tid; p < cnt; p += 256) {
            unsigned long long pr = pairs[beg + p];
            stg[p] = pr;
            atomicAdd(&ldeg[((int)(unsigned)pr) - node0], 1);
        }
    } else {
        for (int p = tid; p < cnt; p += 256)
            atomicAdd(&ldeg[((int)(unsigned)pairs[beg + p]) - node0], 1);
    }
    __syncthreads();
    if (tid < 64) {
        int per = bnodes >> 6;   // 2
        int b0 = tid * per, s = 0;
        for (int j = 0; j < per; ++j) s += ldeg[b0 + j];
        int sc = s;
        for (int o = 1; o < 64; o <<= 1) { int u = __shfl_up(sc, o); if (tid >= o) sc += u; }
        int ex = sc - s;
        for (int j = 0; j < per; ++j) { lrow[b0 + j] = ex; ex += ldeg[b0 + j]; }
    }
    __syncthreads();
    for (int i = tid; i < bnodes; i += 256) {
        int node = node0 + i;
        if (node < n) {
            row_ptr[node] = beg + lrow[i];
            dinv[node] = rsqrtf((float)(ldeg[i] + 1));   // +1 self loop
        }
    }
    if (fit) {
        for (int p = tid; p < cnt; p += 256) {
            unsigned long long pr = stg[p];
            int dl = ((int)(unsigned)pr) - node0;
            int r = atomicAdd(&lcur[dl], 1);
            srcs[beg + lrow[dl] + r] = (int)(pr >> 32);
        }
    } else {
        for (int p = tid; p < cnt; p += 256) {
            unsigned long long pr = pairs[beg + p];
            int dl = ((int)(unsigned)pr) - node0;
            int r = atomicAdd(&lcur[dl], 1);
            srcs[beg + lrow[dl] + r] = (int)(pr >> 32);
        }
    }
}

// ---------- GEMM1: hs = dinv[row] * (x @ W1), bf16 out ----------
// lane = output column. W1 column held in 16 float4 VGPRs (kept resident via
// launch_bounds(256,4) = 128-VGPR budget). x row via wave-uniform s_loads.
// 8 independent accumulator chains (8-deep each) instead of one 64-deep chain.
__global__ __launch_bounds__(256, 4) void k_gemm1(const float* __restrict__ x,
                                                  const float* __restrict__ W,
                                                  const float* __restrict__ dinv,
                                                  unsigned short* __restrict__ h, int n,
                                                  int nwaves) {
    int wid = blockIdx.x * 4 + (threadIdx.x >> 6);
    int lane = threadIdx.x & 63;
    float4 wc[16];   // wc[k4] = W[(4k4..4k4+3)][lane] -> 64 VGPRs
#pragma unroll
    for (int k4 = 0; k4 < 16; ++k4) {
        wc[k4].x = W[(k4 * 4 + 0) * 64 + lane];
        wc[k4].y = W[(k4 * 4 + 1) * 64 + lane];
        wc[k4].z = W[(k4 * 4 + 2) * 64 + lane];
        wc[k4].w = W[(k4 * 4 + 3) * 64 + lane];
    }
    for (int node = wid; node < n; node += nwaves) {
        int node_u = __builtin_amdgcn_readfirstlane(node);
        const float* arow = x + (size_t)node_u * 64;
        float ac0 = 0, ac1 = 0, ac2 = 0, ac3 = 0, ac4 = 0, ac5 = 0, ac6 = 0, ac7 = 0;
#pragma unroll
        for (int k8 = 0; k8 < 8; ++k8) {
            float4 a = *(const float4*)(arow + k8 * 8);       // wave-uniform -> s_load
            float4 c = *(const float4*)(arow + k8 * 8 + 4);
            float4 w0 = wc[k8 * 2], w1 = wc[k8 * 2 + 1];
            ac0 = fmaf(a.x, w0.x, ac0);
            ac1 = fmaf(a.y, w0.y, ac1);
            ac2 = fmaf(a.z, w0.z, ac2);
            ac3 = fmaf(a.w, w0.w, ac3);
            ac4 = fmaf(c.x, w1.x, ac4);
            ac5 = fmaf(c.y, w1.y, ac5);
            ac6 = fmaf(c.z, w1.z, ac6);
            ac7 = fmaf(c.w, w1.w, ac7);
        }
        float acc = ((ac0 + ac1) + (ac2 + ac3)) + ((ac4 + ac5) + (ac6 + ac7));
        h[(size_t)node_u * 64 + lane] = f2bf(acc * dinv[node_u]);
    }
}

// ---------- layer-1 gather: one node per HALF-wave, 4 slots x 8 lanes x uint4 ----------
__global__ __launch_bounds__(256) void k_gather(const uint4* __restrict__ h4,
                                                const int* __restrict__ srcs,
                                                const int* __restrict__ row_ptr,
                                                const float* __restrict__ dinv,
                                                const float* __restrict__ b,
                                                uint4* __restrict__ aggb, int n) {
    int node = (int)(((long long)blockIdx.x * 256 + threadIdx.x) >> 5);
    int l32 = threadIdx.x & 31;
    if (node >= n) return;
    int slot = l32 >> 3, j = l32 & 7;
    float a0x=0,a0y=0,a1x=0,a1y=0,a2x=0,a2y=0,a3x=0,a3y=0;
    if (slot == 0) {
        uint4 u = h4[(size_t)node * 8 + j];
        a0x = bf_lo(u.x); a0y = bf_hi(u.x);
        a1x = bf_lo(u.y); a1y = bf_hi(u.y);
        a2x = bf_lo(u.z); a2y = bf_hi(u.z);
        a3x = bf_lo(u.w); a3y = bf_hi(u.w);
    }
    int e0 = row_ptr[node], cnt = row_ptr[node + 1] - e0;
    int p = slot;
    for (; p + 4 < cnt; p += 8) {
        int s0 = srcs[e0 + p], s1 = srcs[e0 + p + 4];
        uint4 u0 = h4[(size_t)s0 * 8 + j];
        uint4 u1 = h4[(size_t)s1 * 8 + j];
        a0x += bf_lo(u0.x) + bf_lo(u1.x);  a0y += bf_hi(u0.x) + bf_hi(u1.x);
        a1x += bf_lo(u0.y) + bf_lo(u1.y);  a1y += bf_hi(u0.y) + bf_hi(u1.y);
        a2x += bf_lo(u0.z) + bf_lo(u1.z);  a2y += bf_hi(u0.z) + bf_hi(u1.z);
        a3x += bf_lo(u0.w) + bf_lo(u1.w);  a3y += bf_hi(u0.w) + bf_hi(u1.w);
    }
    for (; p < cnt; p += 4) {
        int s0 = srcs[e0 + p];
        uint4 u0 = h4[(size_t)s0 * 8 + j];
        a0x += bf_lo(u0.x);  a0y += bf_hi(u0.x);
        a1x += bf_lo(u0.y);  a1y += bf_hi(u0.y);
        a2x += bf_lo(u0.z);  a2y += bf_hi(u0.z);
        a3x += bf_lo(u0.w);  a3y += bf_hi(u0.w);
    }
#define COMB(o) \
    a0x += __shfl_xor(a0x, o); a0y += __shfl_xor(a0y, o); \
    a1x += __shfl_xor(a1x, o); a1y += __shfl_xor(a1y, o); \
    a2x += __shfl_xor(a2x, o); a2y += __shfl_xor(a2y, o); \
    a3x += __shfl_xor(a3x, o); a3y += __shfl_xor(a3y, o);
    COMB(8) COMB(16)
#undef COMB
    if (slot == 0) {
        float di = dinv[node];
        float4 bl = *(const float4*)&b[8 * j];
        float4 bh = *(const float4*)&b[8 * j + 4];
        float v0 = fmaxf(fmaf(a0x, di, bl.x), 0.0f);
        float v1 = fmaxf(fmaf(a0y, di, bl.y), 0.0f);
        float v2 = fmaxf(fmaf(a1x, di, bl.z), 0.0f);
        float v3 = fmaxf(fmaf(a1y, di, bl.w), 0.0f);
        float v4 = fmaxf(fmaf(a2x, di, bh.x), 0.0f);
        float v5 = fmaxf(fmaf(a2y, di, bh.y), 0.0f);
        float v6 = fmaxf(fmaf(a3x, di, bh.z), 0.0f);
        float v7 = fmaxf(fmaf(a3y, di, bh.w), 0.0f);
        uint4 r;
        r.x = packbf(v0, v1); r.y = packbf(v2, v3);
        r.z = packbf(v4, v5); r.w = packbf(v6, v7);
        aggb[(size_t)node * 8 + j] = r;
    }
}

// ---------- layer-2 transform: ts = dinv * (agg_relu_bf16 @ W2), bf16 ----------
// Same chain-split treatment as k_gemm1: 8 independent accumulators.
__global__ __launch_bounds__(256, 4) void k_trans2(const uint* __restrict__ aggu,
                                                   const float* __restrict__ W2,
                                                   const float* __restrict__ dinv,
                                                   unsigned short* __restrict__ t, int n,
                                                   int nwaves) {
    int wid = blockIdx.x * 4 + (threadIdx.x >> 6);
    int lane = threadIdx.x & 63;
    float wcol[64];
#pragma unroll
    for (int k = 0; k < 64; ++k)
        wcol[k] = (lane < 40) ? W2[k * 40 + lane] : 0.0f;
    for (int node = wid; node < n; node += nwaves) {
        int node_u = __builtin_amdgcn_readfirstlane(node);
        const uint* arow = aggu + (size_t)node_u * 32;
        float ac0 = 0, ac1 = 0, ac2 = 0, ac3 = 0, ac4 = 0, ac5 = 0, ac6 = 0, ac7 = 0;
#pragma unroll
        for (int k4 = 0; k4 < 8; ++k4) {
            uint4 a = *(const uint4*)(arow + k4 * 4);   // wave-uniform -> s_load
            ac0 = fmaf(bf_lo(a.x), wcol[8 * k4 + 0], ac0);
            ac1 = fmaf(bf_hi(a.x), wcol[8 * k4 + 1], ac1);
            ac2 = fmaf(bf_lo(a.y), wcol[8 * k4 + 2], ac2);
            ac3 = fmaf(bf_hi(a.y), wcol[8 * k4 + 3], ac3);
            ac4 = fmaf(bf_lo(a.z), wcol[8 * k4 + 4], ac4);
            ac5 = fmaf(bf_hi(a.z), wcol[8 * k4 + 5], ac5);
            ac6 = fmaf(bf_lo(a.w), wcol[8 * k4 + 6], ac6);
            ac7 = fmaf(bf_hi(a.w), wcol[8 * k4 + 7], ac7);
        }
        float acc = ((ac0 + ac1) + (ac2 + ac3)) + ((ac4 + ac5) + (ac6 + ac7));
        float di = dinv[node_u];
        if (lane < 40) t[(size_t)node_u * 40 + lane] = f2bf(acc * di);
    }
}

// ---------- layer-2 gather: one node per HALF-wave, 3 slots x 10 lanes x uint2 ----------
__global__ __launch_bounds__(256) void k_gather40(const uint2* __restrict__ t2,
                                                  const int* __restrict__ srcs,
                                                  const int* __restrict__ row_ptr,
                                                  const float* __restrict__ dinv,
                                                  const float* __restrict__ b2,
                                                  float* __restrict__ out, int n) {
    int node = (int)(((long long)blockIdx.x * 256 + threadIdx.x) >> 5);
    int lane = threadIdx.x & 63;
    int l32 = lane & 31;
    if (node >= n) return;
    int slot = l32 / 10;             // 0..2 active, 3 idle (l32 30,31)
    int j = l32 - slot * 10;
    bool act = slot < 3;
    float a0=0, a1=0, a2=0, a3=0;
    if (slot == 0) {
        uint2 u = t2[(size_t)node * 10 + j];
        a0 = bf_lo(u.x); a1 = bf_hi(u.x);
        a2 = bf_lo(u.y); a3 = bf_hi(u.y);
    }
    int e0 = row_ptr[node];
    int cnt = act ? (row_ptr[node + 1] - e0) : 0;
    int p = slot;
    for (; p + 3 < cnt; p += 6) {
        int s0 = srcs[e0 + p], s1 = srcs[e0 + p + 3];
        uint2 u0 = t2[(size_t)s0 * 10 + j];
        uint2 u1 = t2[(size_t)s1 * 10 + j];
        a0 += bf_lo(u0.x) + bf_lo(u1.x);  a1 += bf_hi(u0.x) + bf_hi(u1.x);
        a2 += bf_lo(u0.y) + bf_lo(u1.y);  a3 += bf_hi(u0.y) + bf_hi(u1.y);
    }
    for (; p < cnt; p += 3) {
        int s0 = srcs[e0 + p];
        uint2 u0 = t2[(size_t)s0 * 10 + j];
        a0 += bf_lo(u0.x);  a1 += bf_hi(u0.x);
        a2 += bf_lo(u0.y);  a3 += bf_hi(u0.y);
    }
    float t0 = a0 + __shfl(a0, lane + 10) + __shfl(a0, lane + 20);
    float t1 = a1 + __shfl(a1, lane + 10) + __shfl(a1, lane + 20);
    float t2s = a2 + __shfl(a2, lane + 10) + __shfl(a2, lane + 20);
    float t3 = a3 + __shfl(a3, lane + 10) + __shfl(a3, lane + 20);
    bool actc = l32 < 10;
    float di = dinv[node];
    float4 bb = actc ? *(const float4*)&b2[4 * l32] : make_float4(0, 0, 0, 0);
    float v0 = fmaf(t0, di, bb.x);
    float v1 = fmaf(t1, di, bb.y);
    float v2 = fmaf(t2s, di, bb.z);
    float v3 = fmaf(t3, di, bb.w);
    float mv = actc ? fmaxf(fmaxf(v0, v1), fmaxf(v2, v3)) : -INFINITY;
    for (int o = 16; o; o >>= 1) mv = fmaxf(mv, __shfl_xor(mv, o));
    float ex = actc ? (expf(v0 - mv) + expf(v1 - mv) + expf(v2 - mv) + expf(v3 - mv)) : 0.0f;
    float s = ex;
    for (int o = 16; o; o >>= 1) s += __shfl_xor(s, o);
    float ls = mv + logf(s);
    if (actc) {
        float4 r = make_float4(v0 - ls, v1 - ls, v2 - ls, v3 - ls);
        *(float4*)&out[(size_t)node * 40 + 4 * l32] = r;
    }
}

extern "C" void kernel_launch(void* const* d_in, const int* in_sizes, int n_in,
                              void* d_out, int out_size, void* d_ws, size_t ws_size,
                              hipStream_t stream) {
    const float* x  = (const float*)d_in[0];
    const int*   ei = (const int*)d_in[1];
    const float* W1 = (const float*)d_in[2];
    const float* b1 = (const float*)d_in[3];
    const float* W2 = (const float*)d_in[4];
    const float* b2 = (const float*)d_in[5];

    const int N = in_sizes[0] / F1;      // 100000
    const int E = in_sizes[1] / 2;       // 1600000
    const int* src = ei;
    const int* dst = ei + E;

    int bsh = 7;
    while ((((N - 1) >> bsh) + 1) > NB) ++bsh;
    const int NBu = ((N - 1) >> bsh) + 1;   // 782

    // workspace layout (16 B-aligned arrays first)
    uint4* h1b     = (uint4*)d_ws;                                // N*8 uint4 (bf16 hs)
    uint4* aggb    = h1b + (size_t)N * 8;                         // N*8 uint4 (relu agg bf16)
    uint2* tb      = (uint2*)(aggb + (size_t)N * 8);              // N*10 uint2 (bf16 ts)
    unsigned long long* pairs = (unsigned long long*)(tb + (size_t)N * 10);  // E
    int*   srcs    = (int*)(pairs + E);                           // E
    int*   row_ptr = srcs + E;                                    // N+1
    float* dinv    = (float*)(row_ptr + N + 1);                   // N
    int*   bcnt    = (int*)(dinv + N);                            // NB
    int*   bptr    = bcnt + NB;                                   // NB+1
    int*   gcur    = bptr + NB + 1;                               // NB
    float* outp    = (float*)d_out;                               // N*40

    const int B = 256;
    const int GT = (E + TILE - 1) / TILE;

    // --- CSR build (bucketed; emits row_ptr, dinv, srcs) ---
    hipMemsetAsync(bcnt, 0, NB * sizeof(int), stream);
    k_bhist<<<GT, B, 0, stream>>>(dst, bcnt, E, bsh);
    k_bscan<<<1, NB, 0, stream>>>(bcnt, bptr, gcur, row_ptr, N, E);
    k_bscatter<<<GT, B, 0, stream>>>(src, dst, gcur, pairs, E, bsh);
    k_final<<<NBu, B, 0, stream>>>(pairs, bptr, srcs, row_ptr, dinv, N, bsh);

    // --- layer 1: scaled GEMM (bf16, persistent waves) then plain-sum gather ---
    const int TB = 2048;
    k_gemm1<<<TB, B, 0, stream>>>(x, W1, dinv, (unsigned short*)h1b, N, TB * 4);
    k_gather<<<(N + 7) / 8, B, 0, stream>>>(h1b, srcs, row_ptr, dinv, b1, aggb, N);

    // --- layer 2: scaled transform (bf16), plain-sum gather + bias + log_softmax ---
    k_trans2<<<TB, B, 0, stream>>>((const uint*)aggb, W2, dinv, (unsigned short*)tb, N, TB * 4);
    k_gather40<<<(N + 7) / 8, B, 0, stream>>>(tb, srcs, row_ptr, dinv, b2, outp, N);
}